// Round 1
// baseline (255.416 us; speedup 1.0000x reference)
//
#include <hip/hip_runtime.h>

// SphericalBessel: Miller downward recurrence, fp64 internal, fp32 out.
// N=65536, K=32, L=32, lstart = 32 + int(sqrt(320)) = 49.
// out[n, l, k] = y[l] * (sin(x)/x) / y[0] * sqrt(2/pi) * k,  x = r[n]*k.

#define K_MAX 32
#define L_MAX 32
#define LSTART 49  // L_MAX + int(sqrt(10*L_MAX))

__global__ __launch_bounds__(256) void sph_bessel_kernel(
    const float* __restrict__ r, float* __restrict__ out, int n_total) {
    const int tid = blockIdx.x * blockDim.x + threadIdx.x;
    if (tid >= n_total * K_MAX) return;

    const int n  = tid >> 5;   // radius index
    const int kq = tid & 31;   // k index, k = kq+1
    const double kd = (double)(kq + 1);

    const double x   = (double)r[n] * kd;
    const double inv = 1.0 / x;   // reference divides each step; 1 ulp diff is
                                  // benign vs the 2%-of-absmax threshold

    double j1 = 1.0, j2 = 0.0;
    double y[L_MAX];

    // Steps i = 49 .. 33: run the recurrence, discard.
#pragma unroll
    for (int i = LSTART; i > L_MAX; --i) {
        const double j0 = fma((2.0 * i + 1.0) * inv, j1, -j2);
        j2 = j1;
        j1 = j0;
    }
    // Steps i = 32 .. 1: y[i-1] = j0.
#pragma unroll
    for (int i = L_MAX; i >= 1; --i) {
        const double j0 = fma((2.0 * i + 1.0) * inv, j1, -j2);
        j2 = j1;
        j1 = j0;
        y[i - 1] = j0;
    }

    // true j_0(x) = sin(x)/x ; normalize Miller solution and apply sqrt(2/pi)*k.
    const double true_j0 = sin(x) * inv;
    const double scale   = (true_j0 / y[0]) * 0.79788456080286535588 * kd;

    float* op = out + (size_t)n * (L_MAX * K_MAX) + kq;
#pragma unroll
    for (int l = 0; l < L_MAX; ++l) {
        op[(size_t)l * K_MAX] = (float)(y[l] * scale);
    }
}

extern "C" void kernel_launch(void* const* d_in, const int* in_sizes, int n_in,
                              void* d_out, int out_size, void* d_ws, size_t ws_size,
                              hipStream_t stream) {
    const float* r = (const float*)d_in[0];
    float* out = (float*)d_out;
    const int n_total = in_sizes[0];  // 65536

    const int total_threads = n_total * K_MAX;
    const int block = 256;
    const int grid = (total_threads + block - 1) / block;
    sph_bessel_kernel<<<grid, block, 0, stream>>>(r, out, n_total);
}